// Round 9
// baseline (465.721 us; speedup 1.0000x reference)
//
#include <hip/hip_runtime.h>
#include <math.h>

#define NN   100000
#define NE   1600000
#define FIN  256
#define HID  64
#define NC   40
#define NBKT 391          // buckets of 256 nodes: bucket = dst >> 8
#define EPB  6250         // edges per phase-A block (256 * 6250 = NE exactly)
#define CAP  4608         // per-bucket capacity (mean 4092, sd 64 -> 8 sigma slack)
#define NT   6250         // 16-row tiles in gemm1 (6250*16 = NN exactly)
#define NWV  2048         // persistent waves in gemm1 (512 blocks x 4)

typedef __attribute__((ext_vector_type(8))) short short8;
typedef __attribute__((ext_vector_type(4))) float float4v;

static __device__ __forceinline__ short f2bf(float f) {   // RNE f32 -> bf16 bits
    unsigned u = __float_as_uint(f);
    u += 0x7FFFu + ((u >> 16) & 1u);
    return (short)(u >> 16);
}
static __device__ __forceinline__ float bf2f(unsigned short b) {
    return __uint_as_float((unsigned)b << 16);
}

// ---------- W1 -> bf16, transposed to [n][k] ----------
__global__ __launch_bounds__(256) void w1cvt_k(const float* __restrict__ W1,
                                               short* __restrict__ w1t) {
    int t = blockIdx.x * 256 + threadIdx.x;   // 16384
    int k = t >> 6, n = t & 63;
    w1t[n * FIN + k] = f2bf(W1[k * HID + n]);
}

// ---------- phase A: partition edges into 391 coarse buckets ----------
__global__ __launch_bounds__(256) void phaseA_k(const int* __restrict__ src,
                                                const int* __restrict__ dst,
                                                const float* __restrict__ w,
                                                int* __restrict__ cursor,      // [NBKT*16]
                                                int2* __restrict__ bucketbuf) {
    __shared__ int  hist[NBKT];
    __shared__ int  sc[512];
    __shared__ int  loc_base[NBKT];
    __shared__ int  loc_cur[NBKT];
    __shared__ int  gb[NBKT];
    __shared__ int2 buf[EPB];          // 50 KB
    const int t  = threadIdx.x;
    const int e0 = blockIdx.x * EPB;

    for (int i = t; i < NBKT; i += 256) hist[i] = 0;
    __syncthreads();
    for (int i = t; i < EPB; i += 256) atomicAdd(&hist[dst[e0 + i] >> 8], 1);
    __syncthreads();
    sc[t]       = (t       < NBKT) ? hist[t]       : 0;
    sc[t + 256] = (t + 256 < NBKT) ? hist[t + 256] : 0;
    __syncthreads();
    for (int off = 1; off < 512; off <<= 1) {
        int a0 = (t >= off) ? sc[t - off] : 0;
        int a1 = sc[t + 256 - off];
        __syncthreads();
        sc[t] += a0; sc[t + 256] += a1;
        __syncthreads();
    }
    for (int i = t; i < NBKT; i += 256) {
        int base = sc[i] - hist[i];
        loc_base[i] = base;
        loc_cur[i]  = base;
        gb[i] = atomicAdd(&cursor[i * 16], hist[i]);
    }
    __syncthreads();
    for (int i = t; i < EPB; i += 256) {
        int e = e0 + i;
        int d = dst[e];
        int b = d >> 8;
        int p = atomicAdd(&loc_cur[b], 1);
        buf[p] = make_int2(src[e] | ((d & 255) << 17), __float_as_int(w[e]));
    }
    __syncthreads();
    for (int b = t; b < NBKT; b += 256) {
        int lb = loc_base[b], n = hist[b];
        int2* dstp = bucketbuf + (size_t)b * CAP + gb[b];
        for (int i = 0; i < n; ++i) dstp[i] = buf[lb + i];
    }
}

// ---------- scan of bucket counts -> bucket bases ----------
__global__ __launch_bounds__(512) void scanB_k(const int* __restrict__ cursor,
                                               int* __restrict__ bucketbase,
                                               int* __restrict__ row_start) {
    __shared__ int tmp[512];
    int t = threadIdx.x;
    int v = (t < NBKT) ? cursor[t * 16] : 0;
    tmp[t] = v;
    __syncthreads();
    for (int off = 1; off < 512; off <<= 1) {
        int add = (t >= off) ? tmp[t - off] : 0;
        __syncthreads(); tmp[t] += add; __syncthreads();
    }
    if (t < NBKT) bucketbase[t] = tmp[t] - v;
    if (t == 0) { bucketbase[NBKT] = NE; row_start[NN] = NE; }
}

// ---------- phase B: per-bucket CSR build + row_start + dinv ----------
__global__ __launch_bounds__(256) void phaseB_k(const int* __restrict__ bucketbase,
                                                const int2* __restrict__ bucketbuf,
                                                int2* __restrict__ e8,
                                                int* __restrict__ row_start,
                                                float* __restrict__ dinv) {
    __shared__ int2 buf[CAP];
    __shared__ int2 buf2[CAP];
    __shared__ int  hist2[256];
    __shared__ int  tmp[256];
    __shared__ int  base2[257];
    __shared__ int  cur2[256];
    const int b = blockIdx.x, t = threadIdx.x;
    const int g0   = bucketbase[b];
    const int cntb = bucketbase[b + 1] - g0;
    const int n0   = b * 256;
    const int nnb  = (NN - n0 < 256) ? (NN - n0) : 256;

    hist2[t] = 0;
    __syncthreads();
    const int2* bb = bucketbuf + (size_t)b * CAP;
    for (int i = t; i < cntb; i += 256) {
        int2 kv = bb[i];
        buf[i] = kv;
        atomicAdd(&hist2[kv.x >> 17], 1);
    }
    __syncthreads();
    int v = hist2[t];
    tmp[t] = v;
    __syncthreads();
    for (int off = 1; off < 256; off <<= 1) {
        int add = (t >= off) ? tmp[t - off] : 0;
        __syncthreads(); tmp[t] += add; __syncthreads();
    }
    int excl = tmp[t] - v;
    base2[t] = excl;
    cur2[t]  = excl;
    if (t == 0) base2[256] = cntb;
    if (t < nnb) row_start[n0 + t] = g0 + excl;
    __syncthreads();
    for (int i = t; i < cntb; i += 256) {
        int2 kv = buf[i];
        int d = kv.x >> 17;
        int p = atomicAdd(&cur2[d], 1);
        buf2[p] = make_int2(kv.x & 0x1FFFF, kv.y);
    }
    __syncthreads();
    for (int i = t; i < cntb; i += 256) e8[g0 + i] = buf2[i];
    if (t < nnb) {
        float s = 0.f;
        int j1 = base2[t + 1];
        for (int j = base2[t]; j < j1; ++j) s += __int_as_float(buf2[j].y);
        dinv[n0 + t] = rsqrtf(1.0f + s);
    }
}

// ---------- e8scale: fold dinv[src] into edge weights (tables stay raw) ----------
__global__ __launch_bounds__(256) void e8scale_k(int2* __restrict__ e8,
                                                 const float* __restrict__ dinv) {
    int e = blockIdx.x * 256 + threadIdx.x;     // grid 6250 -> NE exactly
    int2 kv = e8[e];
    kv.y = __float_as_int(__int_as_float(kv.y) * dinv[kv.x]);
    e8[e] = kv;
}

// ---------- gemm1 staging: HALF-tile (16 rows x 128 floats = 8KB), source-XOR-swizzled ----------
// instr j loads rows 2j (lanes 0-31) and 2j+1 (lanes 32-63); dest linear, src chunk ^= row&7
static __device__ __forceinline__ void stage_half(const float* __restrict__ x, int t, int h,
                                                  float* buf, int lane) {
#pragma unroll
    for (int j = 0; j < 8; ++j) {
        int row = 2 * j + (lane >> 5);
        int c   = (lane & 31) ^ (row & 7);
        const float* gsrc = x + ((size_t)t * 16 + row) * FIN + h * 128 + c * 4;
        __builtin_amdgcn_global_load_lds(
            (const __attribute__((address_space(1))) void*)gsrc,
            (__attribute__((address_space(3))) void*)(buf + j * 256), 16, 0, 0);
    }
}

// ---------- layer-1 GEMM via MFMA bf16, RAW output: h1[r] = bf16((x@W1)[r]) ----------
// Persistent waves, 2 blocks/CU (64KB LDS/block -> 2 waves/SIMD of TLP), half-K
// double-buffer with counted vmcnt(8): fixed-role buffers bufA=k[0,128) bufB=k[128,256).
__global__ __launch_bounds__(256) void gemm1_mfma_k(const float* __restrict__ x,
                                                    const short* __restrict__ w1t,  // bf16 [64][256]
                                                    unsigned short* __restrict__ h1) {
    __shared__ float xs[4 * 2 * 2048];       // 64 KB: 4 waves x 2 half-buffers x 8KB
    const int wave = threadIdx.x >> 6;
    const int lane = threadIdx.x & 63;
    const int m    = lane & 15;
    const int quad = lane >> 4;
    const int wid  = blockIdx.x * 4 + wave;  // 0..2047

    // preload W1 fragments: bf[nb][kc], 32 x short8 (128 VGPR; 2 waves/SIMD is fine)
    short8 bf[4][8];
#pragma unroll
    for (int nb = 0; nb < 4; ++nb)
#pragma unroll
        for (int kc = 0; kc < 8; ++kc)
            bf[nb][kc] = *(const short8*)(w1t + (nb * 16 + m) * FIN + kc * 32 + quad * 8);

    float* bufA = xs + wave * 4096;
    float* bufB = bufA + 2048;
    const unsigned sw = (unsigned)(m & 7) << 4;   // read-side byte XOR key

#define COMPUTE_HALF(bufh, kbase)                                                        \
    {                                                                                    \
        const char* xrow = (const char*)(bufh) + m * 512;                                \
        _Pragma("unroll")                                                                \
        for (int kcl = 0; kcl < 4; ++kcl) {                                              \
            const unsigned c0 = (unsigned)(kcl * 128 + quad * 32);                       \
            float4v xa = *(const float4v*)(xrow + (c0 ^ sw));                            \
            float4v xb = *(const float4v*)(xrow + ((c0 + 16) ^ sw));                     \
            short8 a;                                                                    \
            a[0]=f2bf(xa[0]); a[1]=f2bf(xa[1]); a[2]=f2bf(xa[2]); a[3]=f2bf(xa[3]);      \
            a[4]=f2bf(xb[0]); a[5]=f2bf(xb[1]); a[6]=f2bf(xb[2]); a[7]=f2bf(xb[3]);      \
            acc0 = __builtin_amdgcn_mfma_f32_16x16x32_bf16(a, bf[0][(kbase)+kcl], acc0, 0, 0, 0); \
            acc1 = __builtin_amdgcn_mfma_f32_16x16x32_bf16(a, bf[1][(kbase)+kcl], acc1, 0, 0, 0); \
            acc2 = __builtin_amdgcn_mfma_f32_16x16x32_bf16(a, bf[2][(kbase)+kcl], acc2, 0, 0, 0); \
            acc3 = __builtin_amdgcn_mfma_f32_16x16x32_bf16(a, bf[3][(kbase)+kcl], acc3, 0, 0, 0); \
        }                                                                                \
    }

    int t = wid;
    if (t < NT) stage_half(x, t, 0, bufA, lane);
    while (t < NT) {
        stage_half(x, t, 1, bufB, lane);
        asm volatile("s_waitcnt vmcnt(8)" ::: "memory");   // bufA landed (drains old stores too)
        __builtin_amdgcn_sched_barrier(0);
        float4v acc0 = {0.f,0.f,0.f,0.f}, acc1 = acc0, acc2 = acc0, acc3 = acc0;
        COMPUTE_HALF(bufA, 0);
        __builtin_amdgcn_sched_barrier(0);

        int tn = t + NWV;
        if (tn < NT) {
            stage_half(x, tn, 0, bufA, lane);
            asm volatile("s_waitcnt vmcnt(8)" ::: "memory");  // bufB landed
        } else {
            asm volatile("s_waitcnt vmcnt(0)" ::: "memory");
        }
        __builtin_amdgcn_sched_barrier(0);
        COMPUTE_HALF(bufB, 4);

        // C/D layout: col = lane&15, row = quad*4 + reg;  NT*16 == NN, no bounds needed
#pragma unroll
        for (int r = 0; r < 4; ++r) {
            int rr = t * 16 + quad * 4 + r;
            unsigned short* hp = h1 + (size_t)rr * HID + m;
            hp[0]  = (unsigned short)f2bf(acc0[r]);
            hp[16] = (unsigned short)f2bf(acc1[r]);
            hp[32] = (unsigned short)f2bf(acc2[r]);
            hp[48] = (unsigned short)f2bf(acc3[r]);
        }
        t = tn;
    }
#undef COMPUTE_HALF
}

// ---------- gatherA: 8 edge-slots x 8 feat-lanes (uint4 = 8 bf16), 2-deep unroll ----------
// weights carry dinv[src]; tables raw. agg1 = dv*acc + dv^2*h[v]; Rp = bf16(relu(agg1+b1))
__global__ __launch_bounds__(256) void gatherA_k(const int* __restrict__ row_start,
                                                 const int2* __restrict__ e8,
                                                 const float* __restrict__ dinv,
                                                 const unsigned short* __restrict__ h,
                                                 const float* __restrict__ b1,
                                                 unsigned short* __restrict__ Rp) {
    const int v    = blockIdx.x * 4 + (threadIdx.x >> 6);
    const int lane = threadIdx.x & 63;
    const int slot = lane >> 3;          // edge slot 0..7
    const int fg   = lane & 7;           // feature group: 8 bf16 = 16 B
    const int i0 = row_start[v], i1 = row_start[v + 1];

    float acc[8] = {0.f,0.f,0.f,0.f,0.f,0.f,0.f,0.f};
    for (int i = i0; i < i1; i += 16) {   // 16 edges per iter -> 16 gathers in flight
        int iiA = i + slot, iiB = i + 8 + slot;
        bool okA = iiA < i1, okB = iiB < i1;
        int2 eA = e8[okA ? iiA : (NE - 1)];
        int2 eB = e8[okB ? iiB : (NE - 1)];
        int  sA = okA ? eA.x : 0;         // OOB slots gather hot row 0, weight 0
        int  sB = okB ? eB.x : 0;
        float wA = okA ? __int_as_float(eA.y) : 0.f;
        float wB = okB ? __int_as_float(eB.y) : 0.f;
        uint4 pA = *(const uint4*)(h + (size_t)sA * HID + fg * 8);
        uint4 pB = *(const uint4*)(h + (size_t)sB * HID + fg * 8);
        acc[0] = fmaf(__uint_as_float(pA.x << 16),         wA, acc[0]);
        acc[1] = fmaf(__uint_as_float(pA.x & 0xFFFF0000u), wA, acc[1]);
        acc[2] = fmaf(__uint_as_float(pA.y << 16),         wA, acc[2]);
        acc[3] = fmaf(__uint_as_float(pA.y & 0xFFFF0000u), wA, acc[3]);
        acc[4] = fmaf(__uint_as_float(pA.z << 16),         wA, acc[4]);
        acc[5] = fmaf(__uint_as_float(pA.z & 0xFFFF0000u), wA, acc[5]);
        acc[6] = fmaf(__uint_as_float(pA.w << 16),         wA, acc[6]);
        acc[7] = fmaf(__uint_as_float(pA.w & 0xFFFF0000u), wA, acc[7]);
        acc[0] = fmaf(__uint_as_float(pB.x << 16),         wB, acc[0]);
        acc[1] = fmaf(__uint_as_float(pB.x & 0xFFFF0000u), wB, acc[1]);
        acc[2] = fmaf(__uint_as_float(pB.y << 16),         wB, acc[2]);
        acc[3] = fmaf(__uint_as_float(pB.y & 0xFFFF0000u), wB, acc[3]);
        acc[4] = fmaf(__uint_as_float(pB.z << 16),         wB, acc[4]);
        acc[5] = fmaf(__uint_as_float(pB.z & 0xFFFF0000u), wB, acc[5]);
        acc[6] = fmaf(__uint_as_float(pB.w << 16),         wB, acc[6]);
        acc[7] = fmaf(__uint_as_float(pB.w & 0xFFFF0000u), wB, acc[7]);
    }
#pragma unroll
    for (int mk = 8; mk <= 32; mk <<= 1) {
#pragma unroll
        for (int q = 0; q < 8; ++q) acc[q] += __shfl_xor(acc[q], mk);
    }

    const float dv  = dinv[v];
    const float dv2 = dv * dv;
    uint4 ps = *(const uint4*)(h + (size_t)v * HID + fg * 8);   // self-loop row (raw)
    float4 bA = *(const float4*)(b1 + fg * 8);
    float4 bB = *(const float4*)(b1 + fg * 8 + 4);
    float r0 = fmaxf(dv * acc[0] + dv2 * __uint_as_float(ps.x << 16)         + bA.x, 0.f);
    float r1 = fmaxf(dv * acc[1] + dv2 * __uint_as_float(ps.x & 0xFFFF0000u) + bA.y, 0.f);
    float r2 = fmaxf(dv * acc[2] + dv2 * __uint_as_float(ps.y << 16)         + bA.z, 0.f);
    float r3 = fmaxf(dv * acc[3] + dv2 * __uint_as_float(ps.y & 0xFFFF0000u) + bA.w, 0.f);
    float r4 = fmaxf(dv * acc[4] + dv2 * __uint_as_float(ps.z << 16)         + bB.x, 0.f);
    float r5 = fmaxf(dv * acc[5] + dv2 * __uint_as_float(ps.z & 0xFFFF0000u) + bB.y, 0.f);
    float r6 = fmaxf(dv * acc[6] + dv2 * __uint_as_float(ps.w << 16)         + bB.z, 0.f);
    float r7 = fmaxf(dv * acc[7] + dv2 * __uint_as_float(ps.w & 0xFFFF0000u) + bB.w, 0.f);
    if (slot == 0) {
        uint4 pk;
        pk.x = (unsigned)(unsigned short)f2bf(r0) | ((unsigned)(unsigned short)f2bf(r1) << 16);
        pk.y = (unsigned)(unsigned short)f2bf(r2) | ((unsigned)(unsigned short)f2bf(r3) << 16);
        pk.z = (unsigned)(unsigned short)f2bf(r4) | ((unsigned)(unsigned short)f2bf(r5) << 16);
        pk.w = (unsigned)(unsigned short)f2bf(r6) | ((unsigned)(unsigned short)f2bf(r7) << 16);
        *(uint4*)(Rp + (size_t)v * HID + fg * 8) = pk;          // raw (weights carry dinv)
    }
}

// ---------- gatherBC: gatherB fused with gemm3+log_softmax (agg2 never materialized) ----------
// After the slot-butterfly every lane holds the full row (8 feats/lane). Lane (slot,fg)
// computes classes [5*slot,5*slot+5) over feats [8*fg,8*fg+8); fg-butterfly sums features,
// slot-butterfly does the softmax reduction. out = logits - logsumexp.
__global__ __launch_bounds__(256) void gatherBC_k(const int* __restrict__ row_start,
                                                  const int2* __restrict__ e8,
                                                  const float* __restrict__ dinv,
                                                  const unsigned short* __restrict__ Rp,
                                                  const float* __restrict__ W2,
                                                  const float* __restrict__ b2,
                                                  float* __restrict__ out) {
    const int v    = blockIdx.x * 4 + (threadIdx.x >> 6);
    const int lane = threadIdx.x & 63;
    const int slot = lane >> 3;
    const int fg   = lane & 7;
    const int i0 = row_start[v], i1 = row_start[v + 1];

    float acc[8] = {0.f,0.f,0.f,0.f,0.f,0.f,0.f,0.f};
    for (int i = i0; i < i1; i += 16) {
        int iiA = i + slot, iiB = i + 8 + slot;
        bool okA = iiA < i1, okB = iiB < i1;
        int2 eA = e8[okA ? iiA : (NE - 1)];
        int2 eB = e8[okB ? iiB : (NE - 1)];
        int  sA = okA ? eA.x : 0;
        int  sB = okB ? eB.x : 0;
        float wA = okA ? __int_as_float(eA.y) : 0.f;
        float wB = okB ? __int_as_float(eB.y) : 0.f;
        uint4 pA = *(const uint4*)(Rp + (size_t)sA * HID + fg * 8);
        uint4 pB = *(const uint4*)(Rp + (size_t)sB * HID + fg * 8);
        acc[0] = fmaf(__uint_as_float(pA.x << 16),         wA, acc[0]);
        acc[1] = fmaf(__uint_as_float(pA.x & 0xFFFF0000u), wA, acc[1]);
        acc[2] = fmaf(__uint_as_float(pA.y << 16),         wA, acc[2]);
        acc[3] = fmaf(__uint_as_float(pA.y & 0xFFFF0000u), wA, acc[3]);
        acc[4] = fmaf(__uint_as_float(pA.z << 16),         wA, acc[4]);
        acc[5] = fmaf(__uint_as_float(pA.z & 0xFFFF0000u), wA, acc[5]);
        acc[6] = fmaf(__uint_as_float(pA.w << 16),         wA, acc[6]);
        acc[7] = fmaf(__uint_as_float(pA.w & 0xFFFF0000u), wA, acc[7]);
        acc[0] = fmaf(__uint_as_float(pB.x << 16),         wB, acc[0]);
        acc[1] = fmaf(__uint_as_float(pB.x & 0xFFFF0000u), wB, acc[1]);
        acc[2] = fmaf(__uint_as_float(pB.y << 16),         wB, acc[2]);
        acc[3] = fmaf(__uint_as_float(pB.y & 0xFFFF0000u), wB, acc[3]);
        acc[4] = fmaf(__uint_as_float(pB.z << 16),         wB, acc[4]);
        acc[5] = fmaf(__uint_as_float(pB.z & 0xFFFF0000u), wB, acc[5]);
        acc[6] = fmaf(__uint_as_float(pB.w << 16),         wB, acc[6]);
        acc[7] = fmaf(__uint_as_float(pB.w & 0xFFFF0000u), wB, acc[7]);
    }
#pragma unroll
    for (int mk = 8; mk <= 32; mk <<= 1) {
#pragma unroll
        for (int q = 0; q < 8; ++q) acc[q] += __shfl_xor(acc[q], mk);
    }

    const float dv  = dinv[v];
    const float dv2 = dv * dv;
    uint4 ps = *(const uint4*)(Rp + (size_t)v * HID + fg * 8);
    float o[8];
    o[0] = dv * acc[0] + dv2 * __uint_as_float(ps.x << 16);
    o[1] = dv * acc[1] + dv2 * __uint_as_float(ps.x & 0xFFFF0000u);
    o[2] = dv * acc[2] + dv2 * __uint_as_float(ps.y << 16);
    o[3] = dv * acc[3] + dv2 * __uint_as_float(ps.y & 0xFFFF0000u);
    o[4] = dv * acc[4] + dv2 * __uint_as_float(ps.z << 16);
    o[5] = dv * acc[5] + dv2 * __uint_as_float(ps.z & 0xFFFF0000u);
    o[6] = dv * acc[6] + dv2 * __uint_as_float(ps.w << 16);
    o[7] = dv * acc[7] + dv2 * __uint_as_float(ps.w & 0xFFFF0000u);

    // W2 slice: rows 8*fg+j (j<8), cols 5*slot..+5 (scalar loads: 4B-aligned only)
    float p0 = b2[5 * slot + 0], p1 = b2[5 * slot + 1], p2 = b2[5 * slot + 2];
    float p3 = b2[5 * slot + 3], p4 = b2[5 * slot + 4];
    const float* wp = W2 + (size_t)(fg * 8) * NC + slot * 5;
#pragma unroll
    for (int j = 0; j < 8; ++j) {
        const float* wr = wp + j * NC;
        float oj = o[j];
        p0 = fmaf(oj, wr[0], p0);
        p1 = fmaf(oj, wr[1], p1);
        p2 = fmaf(oj, wr[2], p2);
        p3 = fmaf(oj, wr[3], p3);
        p4 = fmaf(oj, wr[4], p4);
    }
#pragma unroll
    for (int mk = 1; mk <= 4; mk <<= 1) {        // sum feature-partials over fg
        p0 += __shfl_xor(p0, mk);
        p1 += __shfl_xor(p1, mk);
        p2 += __shfl_xor(p2, mk);
        p3 += __shfl_xor(p3, mk);
        p4 += __shfl_xor(p4, mk);
    }
    float mx = fmaxf(fmaxf(fmaxf(p0, p1), fmaxf(p2, p3)), p4);
#pragma unroll
    for (int mk = 8; mk <= 32; mk <<= 1) mx = fmaxf(mx, __shfl_xor(mx, mk));
    float e = __expf(p0 - mx) + __expf(p1 - mx) + __expf(p2 - mx)
            + __expf(p3 - mx) + __expf(p4 - mx);
#pragma unroll
    for (int mk = 8; mk <= 32; mk <<= 1) e += __shfl_xor(e, mk);
    float lg = mx + __logf(e);
    if (fg == 0) {
        float* op = out + (size_t)v * NC + slot * 5;
        op[0] = p0 - lg; op[1] = p1 - lg; op[2] = p2 - lg; op[3] = p3 - lg; op[4] = p4 - lg;
    }
}

extern "C" void kernel_launch(void* const* d_in, const int* in_sizes, int n_in,
                              void* d_out, int out_size, void* d_ws, size_t ws_size,
                              hipStream_t stream) {
    const float* x  = (const float*)d_in[0];
    const int*   ei = (const int*)d_in[1];     // [2, E]: row0=src, row1=dst
    const float* ea = (const float*)d_in[2];
    const float* W1 = (const float*)d_in[3];
    const float* b1 = (const float*)d_in[4];
    const float* W2 = (const float*)d_in[5];
    const float* b2 = (const float*)d_in[6];
    const int* src = ei;
    const int* dst = ei + NE;
    float* out = (float*)d_out;

    char* ws = (char*)d_ws;
    float* dinv       = (float*)(ws + 0);            //    400,000 B
    int*   row_start  = (int*)  (ws + 400000);       //    400,016 B (NN+1)
    int*   cursor     = (int*)  (ws + 800016);       //     25,024 B (391*16, line-padded)
    int*   bucketbase = (int*)  (ws + 825040);       //      1,568 B
    int2*  e8         = (int2*) (ws + 826608);       // 12,800,000 B
    unsigned short* h1 = (unsigned short*)(ws + 13626608);   // 12,800,000 B (bf16, RAW)
    unsigned short* Rp = (unsigned short*)(ws + 26426608);   // 12,800,000 B (bf16, RAW)
    int2*  bucketbuf  = (int2*) (ws + 39226608);     // 14,418,432 B (phase A/B scratch)
    short* w1t        = (short*)(ws + 64826608);     //     32,768 B -> total 64.86 MB
    hipMemsetAsync(cursor, 0, 391 * 16 * sizeof(int), stream);

    w1cvt_k <<<64,   256, 0, stream>>>(W1, w1t);
    phaseA_k<<<256,  256, 0, stream>>>(src, dst, ea, cursor, bucketbuf);
    scanB_k <<<1,    512, 0, stream>>>(cursor, bucketbase, row_start);
    phaseB_k<<<NBKT, 256, 0, stream>>>(bucketbase, bucketbuf, e8, row_start, dinv);
    e8scale_k<<<NE / 256, 256, 0, stream>>>(e8, dinv);

    gemm1_mfma_k <<<512,  256, 0, stream>>>(x, w1t, h1);
    gatherA_k    <<<NN / 4, 256, 0, stream>>>(row_start, e8, dinv, h1, b1, Rp);
    gatherBC_k   <<<NN / 4, 256, 0, stream>>>(row_start, e8, dinv, Rp, W2, b2, out);
}